// Round 2
// baseline (670.162 us; speedup 1.0000x reference)
//
#include <hip/hip_runtime.h>

#define D 128
#define NUM_GRAPHS 4096

typedef float v4f __attribute__((ext_vector_type(4)));

#define RFL(x) __builtin_amdgcn_readfirstlane(x)

__device__ __forceinline__ float dot4(v4f h, v4f w) {
    return h.x * w.x + h.y * w.y + h.z * w.z + h.w * w.w;
}

// Flush per-lane accumulator to global. Graph ids are wave-uniform scalars
// (cg_e for even rows / half 0, cg_o for odd rows / half 1).
__device__ __forceinline__ void flushv(float* __restrict__ S, float* __restrict__ Z,
                                       int cg_e, int cg_o, int half, int colbase,
                                       bool zlane, v4f& acc, float& zacc) {
    const int cur_g = half ? cg_o : cg_e;
    float* p = &S[(size_t)cur_g * D + colbase];
    atomicAdd(p + 0, acc.x);
    atomicAdd(p + 1, acc.y);
    atomicAdd(p + 2, acc.z);
    atomicAdd(p + 3, acc.w);
    if (zlane) atomicAdd(&Z[cur_g], zacc);
    acc = (v4f)(0.f);
    zacc = 0.f;
}

// Layout: lane l loads float4 -> one 1KB wave-load covers TWO rows.
//   lanes 0..31  = row v   (cols 4*(l&31)..+3)
//   lanes 32..63 = row v+1
// H loads are PLAIN caching loads (NT removed this round: nt-flagged dwordx4
// bypasses L2/L3 assistance and is the prime suspect for the ~1.7 TB/s read
// rate; the 6.4 TB/s fill kernels in the same profile use cached paths).
// Batch ids are wave-uniform s_load_dwordx4, software-prefetched one quad
// ahead together with the H prefetch.
__global__ __launch_bounds__(256) void attn_agg_accum(
    const float* __restrict__ H, const int* __restrict__ batch,
    const float* __restrict__ w, const float* __restrict__ b,
    float* __restrict__ S /* [NUM_GRAPHS*D] = d_out */,
    float* __restrict__ Z /* [NUM_GRAPHS] */,
    int V)
{
    const int lane    = threadIdx.x & 63;
    const int half    = lane >> 5;           // 0: even row of pair, 1: odd row
    const int colbase = (lane & 31) << 2;
    const bool zlane  = (lane & 31) == 0;

    int wid = blockIdx.x * (blockDim.x >> 6) + (threadIdx.x >> 6);
    wid = RFL(wid);                          // pin uniform -> scalar addressing
    const int total_waves = gridDim.x * (blockDim.x >> 6);
    // rows per wave, multiple of 8 so every chunk is whole quads (V=1e6 = 8*125000)
    const int rpw = ((V + total_waves * 8 - 1) / (total_waves * 8)) * 8;

    const int row0 = wid * rpw;
    if (row0 >= V) return;
    int row1 = row0 + rpw;
    if (row1 > V) row1 = V;

    const v4f w4     = ((const v4f*)w)[lane & 31];
    const float bias = b[0];
    const v4f* __restrict__ Hp = (const v4f*)H;   // row r = Hp[r*32 + (lane&31)] per half

    v4f acc    = (v4f)(0.f);
    float zacc = 0.f;

    // current graph of even/odd rows, wave-uniform scalars
    const int2 cgi = *(const int2*)(batch + row0);   // uniform addr, 8B aligned
    int cg_e = RFL(cgi.x);
    int cg_o = RFL(cgi.y);

    int v = row0;
    v4f h0, h1, h2, h3;
    int4 t0, t1;                             // graph ids of current quad (uniform)
    if (v + 8 <= row1) {
        h0 = Hp[(size_t)(v + 0) * 32 + lane];
        h1 = Hp[(size_t)(v + 2) * 32 + lane];
        h2 = Hp[(size_t)(v + 4) * 32 + lane];
        h3 = Hp[(size_t)(v + 6) * 32 + lane];
        t0 = *(const int4*)(batch + v);
        t1 = *(const int4*)(batch + v + 4);
    }

    while (v + 8 <= row1) {
        const int nv = v + 8;

        v4f n0 = h0, n1 = h1, n2 = h2, n3 = h3;
        int4 u0 = t0, u1 = t1;
        if (nv + 8 <= row1) {                    // prefetch next quad (4KB/wave in flight)
            n0 = Hp[(size_t)(nv + 0) * 32 + lane];
            n1 = Hp[(size_t)(nv + 2) * 32 + lane];
            n2 = Hp[(size_t)(nv + 4) * 32 + lane];
            n3 = Hp[(size_t)(nv + 6) * 32 + lane];
            u0 = *(const int4*)(batch + nv);
            u1 = *(const int4*)(batch + nv + 4);
        }

        float d0 = dot4(h0, w4);
        float d1 = dot4(h1, w4);
        float d2 = dot4(h2, w4);
        float d3 = dot4(h3, w4);
        #pragma unroll
        for (int off = 16; off > 0; off >>= 1) {  // stays within each half-wave
            d0 += __shfl_xor(d0, off, 64);
            d1 += __shfl_xor(d1, off, 64);
            d2 += __shfl_xor(d2, off, 64);
            d3 += __shfl_xor(d3, off, 64);
        }

        const float l0 = __expf(d0 + bias);
        const float l1 = __expf(d1 + bias);
        const float l2 = __expf(d2 + bias);
        const float l3 = __expf(d3 + bias);

        const int a0 = RFL(t0.x), a1 = RFL(t0.y), a2 = RFL(t0.z), a3 = RFL(t0.w);
        const int b0 = RFL(t1.x), b1 = RFL(t1.y), b2 = RFL(t1.z), b3 = RFL(t1.w);

        // batch is sorted: whole quad in one graph <=> a0 == b3 (scalar branch)
        if (__builtin_expect(a0 == b3 && a0 == cg_e && a0 == cg_o, 1)) {
            acc += h0 * l0 + h1 * l1 + h2 * l2 + h3 * l3;
            zacc += l0 + l1 + l2 + l3;
        } else {                                  // boundary in quad (~1/30 iters)
            if (a0 != cg_e || a1 != cg_o) { flushv(S, Z, cg_e, cg_o, half, colbase, zlane, acc, zacc); cg_e = a0; cg_o = a1; }
            acc += h0 * l0; zacc += l0;
            if (a2 != cg_e || a3 != cg_o) { flushv(S, Z, cg_e, cg_o, half, colbase, zlane, acc, zacc); cg_e = a2; cg_o = a3; }
            acc += h1 * l1; zacc += l1;
            if (b0 != cg_e || b1 != cg_o) { flushv(S, Z, cg_e, cg_o, half, colbase, zlane, acc, zacc); cg_e = b0; cg_o = b1; }
            acc += h2 * l2; zacc += l2;
            if (b2 != cg_e || b3 != cg_o) { flushv(S, Z, cg_e, cg_o, half, colbase, zlane, acc, zacc); cg_e = b2; cg_o = b3; }
            acc += h3 * l3; zacc += l3;
        }

        h0 = n0; h1 = n1; h2 = n2; h3 = n3;
        t0 = u0; t1 = u1;
        v = nv;
    }

    // pair remainder (chunks are quad-multiples, but keep for safety)
    for (; v + 2 <= row1; v += 2) {
        const int2 t = *(const int2*)(batch + v);    // uniform
        v4f h = Hp[(size_t)v * 32 + lane];
        float d = dot4(h, w4);
        #pragma unroll
        for (int off = 16; off > 0; off >>= 1)
            d += __shfl_xor(d, off, 64);
        const float l = __expf(d + bias);
        const int ge = RFL(t.x), go = RFL(t.y);
        if (ge != cg_e || go != cg_o) { flushv(S, Z, cg_e, cg_o, half, colbase, zlane, acc, zacc); cg_e = ge; cg_o = go; }
        acc += h * l; zacc += l;
    }

    flushv(S, Z, cg_e, cg_o, half, colbase, zlane, acc, zacc);
}

__global__ __launch_bounds__(256) void attn_agg_norm(
    float4* __restrict__ out, const float* __restrict__ Z, int n4)
{
    const int i = blockIdx.x * blockDim.x + threadIdx.x;
    if (i < n4) {
        const int g = i >> 5;            // D == 128 -> 32 float4 per row
        const float z = Z[g];
        float4 o = out[i];
        o.x /= z; o.y /= z; o.z /= z; o.w /= z;
        out[i] = o;
    }
}

extern "C" void kernel_launch(void* const* d_in, const int* in_sizes, int n_in,
                              void* d_out, int out_size, void* d_ws, size_t ws_size,
                              hipStream_t stream) {
    const float* H     = (const float*)d_in[0];
    const int*   batch = (const int*)  d_in[1];
    const float* w     = (const float*)d_in[2];
    const float* b     = (const float*)d_in[3];
    float* out = (float*)d_out;          // [NUM_GRAPHS, D] accumulator + result
    float* Z   = (float*)d_ws;           // [NUM_GRAPHS]

    const int V = in_sizes[0] / D;       // 1,000,000

    hipMemsetAsync(out, 0, (size_t)out_size * sizeof(float), stream);
    hipMemsetAsync(Z,   0, NUM_GRAPHS * sizeof(float), stream);

    // 2048 blocks x 256 threads = 8192 waves; each wave streams 128 rows (16 quads)
    attn_agg_accum<<<2048, 256, 0, stream>>>(H, batch, w, b, out, Z, V);

    const int n4 = NUM_GRAPHS * D / 4;
    attn_agg_norm<<<(n4 + 255) / 256, 256, 0, stream>>>((float4*)out, Z, n4);
}

// Round 4
// 649.659 us; speedup vs baseline: 1.0316x; 1.0316x over previous
//
#include <hip/hip_runtime.h>

#define D 128
#define NUM_GRAPHS 4096

typedef float v4f __attribute__((ext_vector_type(4)));

__device__ __forceinline__ float dot4(v4f h, v4f w) {
    return h.x * w.x + h.y * w.y + h.z * w.z + h.w * w.w;
}

// Flush per-lane accumulator to global. cur_g is PER-LANE (uniform within each
// 32-lane half), so no divergent control flow is ever needed at boundaries.
__device__ __forceinline__ void flushv(float* __restrict__ S, float* __restrict__ Z,
                                       int cur_g, int colbase, bool zlane,
                                       v4f& acc, float& zacc) {
    float* p = &S[(size_t)cur_g * D + colbase];
    atomicAdd(p + 0, acc.x);
    atomicAdd(p + 1, acc.y);
    atomicAdd(p + 2, acc.z);
    atomicAdd(p + 3, acc.w);
    if (zlane) atomicAdd(&Z[cur_g], zacc);
    acc = (v4f)(0.f);
    zacc = 0.f;
}

// Layout: lane l loads float4 -> one 1KB wave-load covers TWO rows.
//   lanes 0..31  = row v   (cols 4*(l&31)..+3)
//   lanes 32..63 = row v+1
// Round-0 structure (best measured: 650.7) + prefetch depth TWO: quads k+1 and
// k+2 are in flight while computing quad k (~8KB/wave), doubling per-wave MLP
// against loaded-latency. Live set ~86 VGPR -> stays under the 128 cliff.
__global__ __launch_bounds__(256) void attn_agg_accum(
    const float* __restrict__ H, const int* __restrict__ batch,
    const float* __restrict__ w, const float* __restrict__ b,
    float* __restrict__ S /* [NUM_GRAPHS*D] = d_out */,
    float* __restrict__ Z /* [NUM_GRAPHS] */,
    int V)
{
    const int lane    = threadIdx.x & 63;
    const int half    = lane >> 5;           // 0: even row of pair, 1: odd row
    const int colbase = (lane & 31) << 2;
    const bool zlane  = (lane & 31) == 0;

    const int wave_id     = blockIdx.x * (blockDim.x >> 6) + (threadIdx.x >> 6);
    const int total_waves = gridDim.x * (blockDim.x >> 6);
    // rows per wave, multiple of 8 so every chunk is whole quads (V=1e6 = 8*125000)
    const int rpw = ((V + total_waves * 8 - 1) / (total_waves * 8)) * 8;

    const int row0 = wave_id * rpw;
    if (row0 >= V) return;
    int row1 = row0 + rpw;
    if (row1 > V) row1 = V;

    const v4f w4     = ((const v4f*)w)[lane & 31];
    const float bias = b[0];
    const v4f* __restrict__ Hp = (const v4f*)H;   // row r = Hp[r*32 + (lane&31)] per half

    v4f acc    = (v4f)(0.f);
    float zacc = 0.f;
    int cur_g  = batch[row0 + half];              // per-lane (row0+1 < V since V even)

    int v = row0;
    // depth-2 software pipeline: A = current quad, B = next, C = next-next (fresh)
    v4f a0, a1, a2, a3, b0, b1, b2, b3;
    int ga0, ga1, ga2, ga3, gb0, gb1, gb2, gb3;
    if (v + 8 <= row1) {
        a0 = __builtin_nontemporal_load(&Hp[(size_t)(v + 0) * 32 + lane]);
        a1 = __builtin_nontemporal_load(&Hp[(size_t)(v + 2) * 32 + lane]);
        a2 = __builtin_nontemporal_load(&Hp[(size_t)(v + 4) * 32 + lane]);
        a3 = __builtin_nontemporal_load(&Hp[(size_t)(v + 6) * 32 + lane]);
        ga0 = batch[v + 0 + half];
        ga1 = batch[v + 2 + half];
        ga2 = batch[v + 4 + half];
        ga3 = batch[v + 6 + half];
        b0 = a0; b1 = a1; b2 = a2; b3 = a3;
        gb0 = ga0; gb1 = ga1; gb2 = ga2; gb3 = ga3;
        if (v + 16 <= row1) {
            b0 = __builtin_nontemporal_load(&Hp[(size_t)(v +  8) * 32 + lane]);
            b1 = __builtin_nontemporal_load(&Hp[(size_t)(v + 10) * 32 + lane]);
            b2 = __builtin_nontemporal_load(&Hp[(size_t)(v + 12) * 32 + lane]);
            b3 = __builtin_nontemporal_load(&Hp[(size_t)(v + 14) * 32 + lane]);
            gb0 = batch[v +  8 + half];
            gb1 = batch[v + 10 + half];
            gb2 = batch[v + 12 + half];
            gb3 = batch[v + 14 + half];
        }
    }

    while (v + 8 <= row1) {
        // rotate-in slot C: prefetch quad v+16 (two ahead)
        v4f c0 = b0, c1 = b1, c2 = b2, c3 = b3;
        int gc0 = gb0, gc1 = gb1, gc2 = gb2, gc3 = gb3;
        if (v + 24 <= row1) {
            c0 = __builtin_nontemporal_load(&Hp[(size_t)(v + 16) * 32 + lane]);
            c1 = __builtin_nontemporal_load(&Hp[(size_t)(v + 18) * 32 + lane]);
            c2 = __builtin_nontemporal_load(&Hp[(size_t)(v + 20) * 32 + lane]);
            c3 = __builtin_nontemporal_load(&Hp[(size_t)(v + 22) * 32 + lane]);
            gc0 = batch[v + 16 + half];
            gc1 = batch[v + 18 + half];
            gc2 = batch[v + 20 + half];
            gc3 = batch[v + 22 + half];
        }

        float d0 = dot4(a0, w4);
        float d1 = dot4(a1, w4);
        float d2 = dot4(a2, w4);
        float d3 = dot4(a3, w4);
        #pragma unroll
        for (int off = 16; off > 0; off >>= 1) {  // stays within each half-wave
            d0 += __shfl_xor(d0, off, 64);
            d1 += __shfl_xor(d1, off, 64);
            d2 += __shfl_xor(d2, off, 64);
            d3 += __shfl_xor(d3, off, 64);
        }

        const float l0 = __expf(d0 + bias);
        const float l1 = __expf(d1 + bias);
        const float l2 = __expf(d2 + bias);
        const float l3 = __expf(d3 + bias);

        const int diff = (ga0 ^ cur_g) | (ga1 ^ cur_g) | (ga2 ^ cur_g) | (ga3 ^ cur_g);
        if (__builtin_expect(!__any(diff), 1)) {  // all 8 rows in current graphs
            acc += a0 * l0 + a1 * l1 + a2 * l2 + a3 * l3;
            zacc += l0 + l1 + l2 + l3;
        } else {                                  // boundary in quad (~1/30 iters)
            if (__any(ga0 ^ cur_g)) { flushv(S, Z, cur_g, colbase, zlane, acc, zacc); cur_g = ga0; }
            acc += a0 * l0; zacc += l0;
            if (__any(ga1 ^ cur_g)) { flushv(S, Z, cur_g, colbase, zlane, acc, zacc); cur_g = ga1; }
            acc += a1 * l1; zacc += l1;
            if (__any(ga2 ^ cur_g)) { flushv(S, Z, cur_g, colbase, zlane, acc, zacc); cur_g = ga2; }
            acc += a2 * l2; zacc += l2;
            if (__any(ga3 ^ cur_g)) { flushv(S, Z, cur_g, colbase, zlane, acc, zacc); cur_g = ga3; }
            acc += a3 * l3; zacc += l3;
        }

        a0 = b0; a1 = b1; a2 = b2; a3 = b3;
        ga0 = gb0; ga1 = gb1; ga2 = gb2; ga3 = gb3;
        b0 = c0; b1 = c1; b2 = c2; b3 = c3;
        gb0 = gc0; gb1 = gc1; gb2 = gc2; gb3 = gc3;
        v += 8;
    }

    // pair remainder (chunks are quad-multiples, but keep for safety)
    for (; v + 2 <= row1; v += 2) {
        v4f h = __builtin_nontemporal_load(&Hp[(size_t)v * 32 + lane]);
        int g = batch[v + half];
        float d = dot4(h, w4);
        #pragma unroll
        for (int off = 16; off > 0; off >>= 1)
            d += __shfl_xor(d, off, 64);
        const float l = __expf(d + bias);
        if (__any(g ^ cur_g)) { flushv(S, Z, cur_g, colbase, zlane, acc, zacc); cur_g = g; }
        acc += h * l; zacc += l;
    }

    flushv(S, Z, cur_g, colbase, zlane, acc, zacc);
}

__global__ __launch_bounds__(256) void attn_agg_norm(
    float4* __restrict__ out, const float* __restrict__ Z, int n4)
{
    const int i = blockIdx.x * blockDim.x + threadIdx.x;
    if (i < n4) {
        const int g = i >> 5;            // D == 128 -> 32 float4 per row
        const float z = Z[g];
        float4 o = out[i];
        o.x /= z; o.y /= z; o.z /= z; o.w /= z;
        out[i] = o;
    }
}

extern "C" void kernel_launch(void* const* d_in, const int* in_sizes, int n_in,
                              void* d_out, int out_size, void* d_ws, size_t ws_size,
                              hipStream_t stream) {
    const float* H     = (const float*)d_in[0];
    const int*   batch = (const int*)  d_in[1];
    const float* w     = (const float*)d_in[2];
    const float* b     = (const float*)d_in[3];
    float* out = (float*)d_out;          // [NUM_GRAPHS, D] accumulator + result
    float* Z   = (float*)d_ws;           // [NUM_GRAPHS]

    const int V = in_sizes[0] / D;       // 1,000,000

    hipMemsetAsync(out, 0, (size_t)out_size * sizeof(float), stream);
    hipMemsetAsync(Z,   0, NUM_GRAPHS * sizeof(float), stream);

    // 2048 blocks x 256 threads = 8192 waves; each wave streams 128 rows (16 quads)
    attn_agg_accum<<<2048, 256, 0, stream>>>(H, batch, w, b, out, Z, V);

    const int n4 = NUM_GRAPHS * D / 4;
    attn_agg_norm<<<(n4 + 255) / 256, 256, 0, stream>>>((float4*)out, Z, n4);
}